// Round 2
// baseline (249.947 us; speedup 1.0000x reference)
//
#include <hip/hip_runtime.h>
#include <math.h>

// ClownSelector: windowed router, LDS-free lane-per-expert design.
//
// lane = expert (E=64 == wave width). Each wave computes 8 output tokens:
//   - 10 dot-rows (8 + 2-row causal halo, clamped to token 0)
//   - proto chunk (64 d-values for this lane's expert) lives in 64 VGPRs,
//     loaded coalesced from a repacked protoTT[d/4][e] workspace
//   - x values are wave-uniform (readfirstlane'd base) -> scalar/broadcast
//     loads; one v_fma per (d, row) performs 64 expert-MACs across lanes
//   - L2 norm: coalesced partial + 6-step shfl_xor butterfly
//   - top-2 + renorm-softmax: w1 = 1/(1+exp((l2-l1)/3)); softmax sum cancels
// No LDS, no barriers, no atomics. 2048 independent waves (2/SIMD).

#define BB 8
#define SS 2048
#define DD 1024
#define EE 64
#define RPW 8             // output tokens per wave
#define HALO 2
#define NR (RPW + HALO)   // 10 dot rows per wave
#define NCHUNK 16         // d-chunks of 64
#define EPSV 1e-8f

// ---- Kernel A: repack proto[e][d] -> protoTT_f4[dd][e], dd = d/4 ----------
__global__ __launch_bounds__(256) void repack_proto(
    const float* __restrict__ proto, float4* __restrict__ ptt) {
  const int gid = blockIdx.x * 256 + threadIdx.x;  // 0..16383
  const int dd = gid >> 6;
  const int e  = gid & 63;
  ptt[gid] = *(const float4*)(proto + (size_t)e * DD + dd * 4);
}

// ---- Kernel B: fused norms + GEMM + window + top2 --------------------------
__global__ __launch_bounds__(256) void router_main(
    const float* __restrict__ x, const float4* __restrict__ ptt,
    float* __restrict__ out) {
  const int lane = threadIdx.x & 63;
  // wave id, forced wave-uniform so x addressing scalarizes
  const int wid = __builtin_amdgcn_readfirstlane(
      blockIdx.x * 4 + (threadIdx.x >> 6));      // 0..2047
  const int b  = wid >> 8;
  const int s0 = (wid & 255) * RPW;

  const float* xb = x + (size_t)b * SS * DD;

  // clamped row indices (causal halo replicates token 0) — wave-uniform
  int rs[NR];
#pragma unroll
  for (int i = 0; i < NR; ++i) {
    int s = s0 - HALO + i;
    rs[i] = s < 0 ? 0 : s;
  }

  // ---- per-row 1/max(||x||,eps): coalesced partial + butterfly reduce ----
  float inv[NR];
#pragma unroll
  for (int i = 0; i < NR; ++i) {
    const float4* xr = (const float4*)(xb + (size_t)rs[i] * DD);
    float ss = 0.0f;
#pragma unroll
    for (int j = 0; j < 4; ++j) {
      const float4 v = xr[j * 64 + lane];  // lane-contiguous, coalesced
      ss += v.x * v.x + v.y * v.y + v.z * v.z + v.w * v.w;
    }
#pragma unroll
    for (int m = 1; m < 64; m <<= 1) ss += __shfl_xor(ss, m);
    inv[i] = 1.0f / fmaxf(sqrtf(ss), EPSV);
  }

  // ---- GEMM: acc[row] for this lane's expert ----
  float acc[NR];
#pragma unroll
  for (int i = 0; i < NR; ++i) acc[i] = 0.0f;

  for (int c = 0; c < NCHUNK; ++c) {
    // proto chunk: 64 d-values for expert `lane` (coalesced, 16B/lane)
    float4 p4[16];
#pragma unroll
    for (int dq = 0; dq < 16; ++dq) p4[dq] = ptt[(c * 16 + dq) * 64 + lane];
#pragma unroll
    for (int i = 0; i < NR; ++i) {
      const float4* xr = (const float4*)(xb + (size_t)rs[i] * DD + c * 64);
#pragma unroll
      for (int dq = 0; dq < 16; ++dq) {
        const float4 v = xr[dq];  // wave-uniform address -> scalar/broadcast
        acc[i] += v.x * p4[dq].x;
        acc[i] += v.y * p4[dq].y;
        acc[i] += v.z * p4[dq].z;
        acc[i] += v.w * p4[dq].w;
      }
    }
  }

  // ---- normalized dots, window-3 sums, per-token top-2 ----
  float nd[NR];
#pragma unroll
  for (int i = 0; i < NR; ++i) nd[i] = acc[i] * inv[i];

#pragma unroll
  for (int i = 0; i < RPW; ++i) {
    float v1 = nd[i] + nd[i + 1] + nd[i + 2];  // window sum (mean*3)
    int   i1 = lane;
    float v2 = -INFINITY;
    int   i2 = 0;
#pragma unroll
    for (int m = 1; m < 64; m <<= 1) {
      const float ov1 = __shfl_xor(v1, m);
      const int   oi1 = __shfl_xor(i1, m);
      const float ov2 = __shfl_xor(v2, m);
      const int   oi2 = __shfl_xor(i2, m);
      const bool o_beats = (ov1 > v1) || (ov1 == v1 && oi1 < i1);
      if (o_beats) {
        const bool v1_beats_o2 = (v1 > ov2) || (v1 == ov2 && i1 < oi2);
        v2 = v1_beats_o2 ? v1 : ov2;
        i2 = v1_beats_o2 ? i1 : oi2;
        v1 = ov1;
        i1 = oi1;
      } else {
        const bool o1_beats_v2 = (ov1 > v2) || (ov1 == v2 && oi1 < i2);
        if (o1_beats_v2) { v2 = ov1; i2 = oi1; }
      }
    }
    if (lane == 0) {
      // implicit /3 window mean: only the top-2 logit gap matters
      const float ex = expf((v2 - v1) * (1.0f / 3.0f));  // <= 1
      const float w1 = 1.0f / (1.0f + ex);
      const size_t t = ((size_t)b * SS + s0 + i) * 2;
      *(float2*)(out + t) = make_float2((float)i1, (float)i2);
      *(float2*)(out + (size_t)BB * SS * 2 + t) = make_float2(w1, ex * w1);
    }
  }
}

extern "C" void kernel_launch(void* const* d_in, const int* in_sizes, int n_in,
                              void* d_out, int out_size, void* d_ws, size_t ws_size,
                              hipStream_t stream) {
  const float* x     = (const float*)d_in[0];
  const float* proto = (const float*)d_in[1];
  // d_in[2] = attn_mask: unused by the reference output path.
  float* out = (float*)d_out;
  float4* ptt = (float4*)d_ws;  // 256 KiB repacked prototypes

  repack_proto<<<dim3(64), dim3(256), 0, stream>>>(proto, ptt);
  // 2048 waves = 512 blocks x 4 waves; 8 tokens per wave
  router_main<<<dim3(512), dim3(256), 0, stream>>>(x, ptt, out);
}